// Round 1
// baseline (305.789 us; speedup 1.0000x reference)
//
#include <hip/hip_runtime.h>
#include <hip/hip_bf16.h>

#define HEADS 16
#define SEQ   2048
#define EMB   1024
#define BATCH 2
#define DHEAD 64
#define MTOK  (BATCH * SEQ)   // 4096

typedef __bf16 bf16x8 __attribute__((ext_vector_type(8)));
typedef float  floatx4 __attribute__((ext_vector_type(4)));

__device__ __forceinline__ void gl_lds16(const void* g, void* l) {
  // async global->LDS, 16B/lane; LDS dest = wave-uniform base + lane*16
  __builtin_amdgcn_global_load_lds((__attribute__((address_space(1))) void*)(g),
                                   (__attribute__((address_space(3))) void*)(l), 16, 0, 0);
}

__device__ __forceinline__ unsigned short f2bf(float f) {
  unsigned int u = __builtin_bit_cast(unsigned int, f);
  u = (u + 0x7FFFu + ((u >> 16) & 1u)) >> 16;   // RNE
  return (unsigned short)u;
}

// ---------------- fp32 -> bf16 conversion (x + 4 weights) ----------------
__global__ __launch_bounds__(256) void cvt_kernel(
    const float* __restrict__ x,  const float* __restrict__ wq,
    const float* __restrict__ wk, const float* __restrict__ wv,
    const float* __restrict__ wu,
    unsigned short* __restrict__ xb,  unsigned short* __restrict__ wqb,
    unsigned short* __restrict__ wkb, unsigned short* __restrict__ wvb,
    unsigned short* __restrict__ wub) {
  const int g = blockIdx.x * 256 + threadIdx.x;  // granule of 4 floats
  const int XG = (MTOK * EMB) / 4;               // 1048576
  const int WG = (EMB * EMB) / 4;                // 262144
  const float* src; unsigned short* dst; int off;
  if (g < XG) { src = x; dst = xb; off = g; }
  else {
    int t = g - XG; int wsel = t / WG; off = t - wsel * WG;
    const float* ss[4] = {wq, wk, wv, wu};
    unsigned short* dd[4] = {wqb, wkb, wvb, wub};
    src = ss[wsel]; dst = dd[wsel];
  }
  float4 v = ((const float4*)src)[off];
  ushort4 o;
  o.x = f2bf(v.x); o.y = f2bf(v.y); o.z = f2bf(v.z); o.w = f2bf(v.w);
  ((ushort4*)dst)[off] = o;
}

// ---------------- fused QKV projection: y = x @ W^T (NT GEMM) ----------------
// 128x128 tile, BK=32, 256 thr / 4 waves, each wave 64x64 via 4x4 16x16x32 MFMA.
// z=0 -> Q [tok][E], z=1 -> K [tok][E], z=2 -> V transposed [B*H][D][S].
__global__ __launch_bounds__(256) void gemm_qkv(
    const unsigned short* __restrict__ xb,
    const unsigned short* __restrict__ wqb, const unsigned short* __restrict__ wkb,
    const unsigned short* __restrict__ wvb,
    unsigned short* __restrict__ Qb, unsigned short* __restrict__ Kb,
    unsigned short* __restrict__ Vt) {
  constexpr int BM = 128, BN = 128, BK = 32;
  __shared__ unsigned short As[BM * BK];
  __shared__ unsigned short Bs[BN * BK];
  const int z = blockIdx.z;
  const unsigned short* W = (z == 0) ? wqb : (z == 1) ? wkb : wvb;
  const int m0 = blockIdx.x * BM, n0 = blockIdx.y * BN;
  const int tid = threadIdx.x, w = tid >> 6, lane = tid & 63;
  const int quad = lane >> 4, l16 = lane & 15;
  const int wm = w >> 1, wn = w & 1;
  const int srow = lane >> 2, skoff = (lane & 3) * 8;

  floatx4 acc[4][4] = {};

  for (int kt = 0; kt < EMB / BK; ++kt) {
    const int k0 = kt * BK;
#pragma unroll
    for (int i = 0; i < BM / 64; ++i) {
      int r = i * 64 + w * 16;
      gl_lds16(xb + (size_t)(m0 + r + srow) * EMB + k0 + skoff, &As[r * BK]);
    }
#pragma unroll
    for (int i = 0; i < BN / 64; ++i) {
      int r = i * 64 + w * 16;
      gl_lds16(W + (size_t)(n0 + r + srow) * EMB + k0 + skoff, &Bs[r * BK]);
    }
    __syncthreads();
    bf16x8 af[4], bfv[4];
#pragma unroll
    for (int mb = 0; mb < 4; ++mb)
      af[mb] = *(const bf16x8*)&As[(wm * 64 + mb * 16 + l16) * BK + quad * 8];
#pragma unroll
    for (int nb = 0; nb < 4; ++nb)
      bfv[nb] = *(const bf16x8*)&Bs[(wn * 64 + nb * 16 + l16) * BK + quad * 8];
#pragma unroll
    for (int mb = 0; mb < 4; ++mb)
#pragma unroll
      for (int nb = 0; nb < 4; ++nb)
        acc[mb][nb] = __builtin_amdgcn_mfma_f32_16x16x32_bf16(af[mb], bfv[nb], acc[mb][nb], 0, 0, 0);
    __syncthreads();
  }

  if (z < 2) {
    unsigned short* C = (z == 0) ? Qb : Kb;
#pragma unroll
    for (int mb = 0; mb < 4; ++mb) {
#pragma unroll
      for (int nb = 0; nb < 4; ++nb) {
        int n = n0 + wn * 64 + nb * 16 + l16;
#pragma unroll
        for (int r = 0; r < 4; ++r) {
          int m = m0 + wm * 64 + mb * 16 + quad * 4 + r;
          C[(size_t)m * EMB + n] = f2bf(acc[mb][nb][r]);
        }
      }
    }
  } else {
    // transposed store: Vt[(b*1024 + n)][s], n = h*64+d, 4 consecutive s per lane
#pragma unroll
    for (int mb = 0; mb < 4; ++mb) {
      int mbase = m0 + wm * 64 + mb * 16 + quad * 4;
      int b = mbase >> 11, s = mbase & (SEQ - 1);
#pragma unroll
      for (int nb = 0; nb < 4; ++nb) {
        int n = n0 + wn * 64 + nb * 16 + l16;
        ushort4 o;
        o.x = f2bf(acc[mb][nb][0]); o.y = f2bf(acc[mb][nb][1]);
        o.z = f2bf(acc[mb][nb][2]); o.w = f2bf(acc[mb][nb][3]);
        *(ushort4*)&Vt[((size_t)b * (HEADS * DHEAD) + n) * SEQ + s] = o;
      }
    }
  }
}

// ---------------- flash-style causal attention ----------------
// grid (qt=32, bh=32); block 256 = 4 waves; wave w owns Q rows q0+16w..+15.
// KT=64 keys/iter; online softmax in exp2 domain; P via LDS round-trip.
__global__ __launch_bounds__(256) void attn_kernel(
    const unsigned short* __restrict__ Qb, const unsigned short* __restrict__ Kb,
    const unsigned short* __restrict__ Vt, unsigned short* __restrict__ ctx) {
  constexpr int QT = 64, KT = 64;
  __shared__ unsigned short Ks[KT * DHEAD];   // [key][d]
  __shared__ unsigned short Vs[DHEAD * KT];   // [d][key]  (V^T)
  __shared__ unsigned short Ps[4 * 16 * KT];  // per-wave [16][64]
  const int qt = blockIdx.x, bh = blockIdx.y;
  const int b = bh >> 4, h = bh & 15;
  const int q0 = qt * QT;
  const int tid = threadIdx.x, w = tid >> 6, lane = tid & 63;
  const int quad = lane >> 4, l16 = lane & 15;

  const size_t qrow = (size_t)(b * SEQ + q0 + w * 16 + l16) * EMB + h * DHEAD;
  bf16x8 qf[2];
  qf[0] = *(const bf16x8*)&Qb[qrow + quad * 8];
  qf[1] = *(const bf16x8*)&Qb[qrow + 32 + quad * 8];

  float mrow[4], lrow[4];
  floatx4 acc_o[4] = {};
#pragma unroll
  for (int r = 0; r < 4; ++r) { mrow[r] = -1e30f; lrow[r] = 0.0f; }

  const float sc = 0.125f * 1.44269504088896f;  // 1/sqrt(D) * log2(e)

  for (int kt = 0; kt <= qt; ++kt) {
    const int kt0 = kt * KT;
#pragma unroll
    for (int i = 0; i < 2; ++i) {
      int c = i * 256 + w * 64 + lane;          // chunk id: 8 bf16 each
      gl_lds16(Kb + (size_t)(b * SEQ + kt0 + (c >> 3)) * EMB + h * DHEAD + (c & 7) * 8,
               &Ks[(i * 256 + w * 64) * 8]);
      gl_lds16(Vt + ((size_t)bh * DHEAD + (c >> 3)) * SEQ + kt0 + (c & 7) * 8,
               &Vs[(i * 256 + w * 64) * 8]);
    }
    __syncthreads();

    // S = Q K^T (wave's 16 rows x 64 keys)
    floatx4 accs[4] = {};
#pragma unroll
    for (int ks = 0; ks < 2; ++ks)
#pragma unroll
      for (int nb = 0; nb < 4; ++nb) {
        bf16x8 kf = *(const bf16x8*)&Ks[(nb * 16 + l16) * DHEAD + ks * 32 + quad * 8];
        accs[nb] = __builtin_amdgcn_mfma_f32_16x16x32_bf16(qf[ks], kf, accs[nb], 0, 0, 0);
      }

    float sv[4][4];
    const bool diag = (kt == qt);
#pragma unroll
    for (int nb = 0; nb < 4; ++nb) {
      int col = kt0 + nb * 16 + l16;
#pragma unroll
      for (int r = 0; r < 4; ++r) {
        float v = accs[nb][r] * sc;
        if (diag) {
          int row = q0 + w * 16 + quad * 4 + r;
          if (col > row) v = -1e30f;
        }
        sv[nb][r] = v;
      }
    }

    // online softmax per row (rows quad*4+r, replicated across 16-lane group)
    float p[4][4];
#pragma unroll
    for (int r = 0; r < 4; ++r) {
      float rm = fmaxf(fmaxf(sv[0][r], sv[1][r]), fmaxf(sv[2][r], sv[3][r]));
      rm = fmaxf(rm, __shfl_xor(rm, 1));
      rm = fmaxf(rm, __shfl_xor(rm, 2));
      rm = fmaxf(rm, __shfl_xor(rm, 4));
      rm = fmaxf(rm, __shfl_xor(rm, 8));
      float mnew = fmaxf(mrow[r], rm);
      float alpha = exp2f(mrow[r] - mnew);
      float rs = 0.0f;
#pragma unroll
      for (int nb = 0; nb < 4; ++nb) {
        float pe = exp2f(sv[nb][r] - mnew);
        p[nb][r] = pe; rs += pe;
      }
      rs += __shfl_xor(rs, 1);
      rs += __shfl_xor(rs, 2);
      rs += __shfl_xor(rs, 4);
      rs += __shfl_xor(rs, 8);
      lrow[r] = lrow[r] * alpha + rs;
      mrow[r] = mnew;
#pragma unroll
      for (int nb = 0; nb < 4; ++nb) acc_o[nb][r] *= alpha;
    }

    // P -> LDS (C-layout write), reread as A-operand
#pragma unroll
    for (int nb = 0; nb < 4; ++nb)
#pragma unroll
      for (int r = 0; r < 4; ++r)
        Ps[w * (16 * KT) + (quad * 4 + r) * KT + nb * 16 + l16] = f2bf(p[nb][r]);
    __syncthreads();

#pragma unroll
    for (int ks = 0; ks < 2; ++ks) {
      bf16x8 pf = *(const bf16x8*)&Ps[w * (16 * KT) + l16 * KT + ks * 32 + quad * 8];
#pragma unroll
      for (int nb = 0; nb < 4; ++nb) {
        bf16x8 vf = *(const bf16x8*)&Vs[(nb * 16 + l16) * KT + ks * 32 + quad * 8];
        acc_o[nb] = __builtin_amdgcn_mfma_f32_16x16x32_bf16(pf, vf, acc_o[nb], 0, 0, 0);
      }
    }
    __syncthreads();
  }

  // normalize + write ctx [tok][E]
#pragma unroll
  for (int r = 0; r < 4; ++r) {
    float inv = 1.0f / lrow[r];
    int m = q0 + w * 16 + quad * 4 + r;
    size_t base = (size_t)(b * SEQ + m) * EMB + h * DHEAD;
#pragma unroll
    for (int nb = 0; nb < 4; ++nb)
      ctx[base + nb * 16 + l16] = f2bf(acc_o[nb][r] * inv);
  }
}

// ---------------- output projection: out = ctx @ Wu^T + bu (fp32 out) ----------------
// 128x64 tile -> 512 blocks for occupancy; wave tile 64x32 (4x2 MFMA grid).
__global__ __launch_bounds__(256) void gemm_out(
    const unsigned short* __restrict__ ctx, const unsigned short* __restrict__ wub,
    const float* __restrict__ bu, float* __restrict__ out) {
  constexpr int BM = 128, BN = 64, BK = 32;
  __shared__ unsigned short As[BM * BK];
  __shared__ unsigned short Bs[BN * BK];
  const int m0 = blockIdx.x * BM, n0 = blockIdx.y * BN;
  const int tid = threadIdx.x, w = tid >> 6, lane = tid & 63;
  const int quad = lane >> 4, l16 = lane & 15;
  const int wm = w >> 1, wn = w & 1;
  const int srow = lane >> 2, skoff = (lane & 3) * 8;

  floatx4 acc[4][2] = {};

  for (int kt = 0; kt < EMB / BK; ++kt) {
    const int k0 = kt * BK;
#pragma unroll
    for (int i = 0; i < 2; ++i) {
      int r = i * 64 + w * 16;
      gl_lds16(ctx + (size_t)(m0 + r + srow) * EMB + k0 + skoff, &As[r * BK]);
    }
    gl_lds16(wub + (size_t)(n0 + w * 16 + srow) * EMB + k0 + skoff, &Bs[(w * 16) * BK]);
    __syncthreads();
    bf16x8 af[4], bfv[2];
#pragma unroll
    for (int mb = 0; mb < 4; ++mb)
      af[mb] = *(const bf16x8*)&As[(wm * 64 + mb * 16 + l16) * BK + quad * 8];
#pragma unroll
    for (int nb = 0; nb < 2; ++nb)
      bfv[nb] = *(const bf16x8*)&Bs[(wn * 32 + nb * 16 + l16) * BK + quad * 8];
#pragma unroll
    for (int mb = 0; mb < 4; ++mb)
#pragma unroll
      for (int nb = 0; nb < 2; ++nb)
        acc[mb][nb] = __builtin_amdgcn_mfma_f32_16x16x32_bf16(af[mb], bfv[nb], acc[mb][nb], 0, 0, 0);
    __syncthreads();
  }

#pragma unroll
  for (int mb = 0; mb < 4; ++mb) {
#pragma unroll
    for (int nb = 0; nb < 2; ++nb) {
      int n = n0 + wn * 32 + nb * 16 + l16;
      float bias = bu[n];
#pragma unroll
      for (int r = 0; r < 4; ++r) {
        int m = m0 + wm * 64 + mb * 16 + quad * 4 + r;
        out[(size_t)m * EMB + n] = acc[mb][nb][r] + bias;
      }
    }
  }
}

extern "C" void kernel_launch(void* const* d_in, const int* in_sizes, int n_in,
                              void* d_out, int out_size, void* d_ws, size_t ws_size,
                              hipStream_t stream) {
  // setup_inputs order: x, Wk, Wq, Wv, Wu, bu
  const float* x  = (const float*)d_in[0];
  const float* Wk = (const float*)d_in[1];
  const float* Wq = (const float*)d_in[2];
  const float* Wv = (const float*)d_in[3];
  const float* Wu = (const float*)d_in[4];
  const float* bu = (const float*)d_in[5];

  char* ws = (char*)d_ws;
  const size_t MB1 = 1 << 20;
  unsigned short* xb  = (unsigned short*)(ws + 0);
  unsigned short* wqb = (unsigned short*)(ws + 8  * MB1);
  unsigned short* wkb = (unsigned short*)(ws + 10 * MB1);
  unsigned short* wvb = (unsigned short*)(ws + 12 * MB1);
  unsigned short* wub = (unsigned short*)(ws + 14 * MB1);
  unsigned short* Qb  = (unsigned short*)(ws + 16 * MB1);
  unsigned short* Kb  = (unsigned short*)(ws + 24 * MB1);
  unsigned short* Vt  = (unsigned short*)(ws + 32 * MB1);
  unsigned short* ctx = (unsigned short*)(ws + 40 * MB1);

  cvt_kernel<<<8192, 256, 0, stream>>>(x, Wq, Wk, Wv, Wu, xb, wqb, wkb, wvb, wub);
  gemm_qkv<<<dim3(32, 8, 3), 256, 0, stream>>>(xb, wqb, wkb, wvb, Qb, Kb, Vt);
  attn_kernel<<<dim3(32, 32), 256, 0, stream>>>(Qb, Kb, Vt, ctx);
  gemm_out<<<dim3(32, 16), 256, 0, stream>>>(ctx, wub, bu, (float*)d_out);
}

// Round 2
// 200.387 us; speedup vs baseline: 1.5260x; 1.5260x over previous
//
#include <hip/hip_runtime.h>
#include <hip/hip_bf16.h>

#define HEADS 16
#define SEQ   2048
#define EMB   1024
#define BATCH 2
#define DHEAD 64
#define MTOK  (BATCH * SEQ)   // 4096

typedef __bf16 bf16x8 __attribute__((ext_vector_type(8)));
typedef float  floatx4 __attribute__((ext_vector_type(4)));

#if __has_builtin(__builtin_amdgcn_exp2f)
#define EXP2(x) __builtin_amdgcn_exp2f(x)
#else
#define EXP2(x) exp2f(x)
#endif

__device__ __forceinline__ void gl_lds16(const void* g, void* l) {
  // async global->LDS, 16B/lane; LDS dest = wave-uniform base + lane*16
  __builtin_amdgcn_global_load_lds((__attribute__((address_space(1))) void*)(g),
                                   (__attribute__((address_space(3))) void*)(l), 16, 0, 0);
}

__device__ __forceinline__ unsigned short f2bf(float f) {
  __bf16 h = (__bf16)f;                      // native cvt, RNE
  return __builtin_bit_cast(unsigned short, h);
}

// ---------------- fp32 -> bf16 conversion (x + 4 weights) ----------------
__global__ __launch_bounds__(256) void cvt_kernel(
    const float* __restrict__ x,  const float* __restrict__ wq,
    const float* __restrict__ wk, const float* __restrict__ wv,
    const float* __restrict__ wu,
    unsigned short* __restrict__ xb,  unsigned short* __restrict__ wqb,
    unsigned short* __restrict__ wkb, unsigned short* __restrict__ wvb,
    unsigned short* __restrict__ wub) {
  const int g = blockIdx.x * 256 + threadIdx.x;  // granule of 4 floats
  const int XG = (MTOK * EMB) / 4;               // 1048576
  const int WG = (EMB * EMB) / 4;                // 262144
  const float* src; unsigned short* dst; int off;
  if (g < XG) { src = x; dst = xb; off = g; }
  else {
    int t = g - XG; int wsel = t / WG; off = t - wsel * WG;
    const float* ss[4] = {wq, wk, wv, wu};
    unsigned short* dd[4] = {wqb, wkb, wvb, wub};
    src = ss[wsel]; dst = dd[wsel];
  }
  float4 v = ((const float4*)src)[off];
  ushort4 o;
  o.x = f2bf(v.x); o.y = f2bf(v.y); o.z = f2bf(v.z); o.w = f2bf(v.w);
  ((ushort4*)dst)[off] = o;
}

// ---------------- fused QKV projection: y = x @ W^T (NT GEMM) ----------------
// 128x128 tile, BK=32, 256 thr / 4 waves, each wave 64x64 via 4x4 16x16x32 MFMA.
// z=0 -> Q*(0.125*log2e) [tok][E], z=1 -> K [tok][E], z=2 -> V^T per-batch [B][E][S].
__global__ __launch_bounds__(256) void gemm_qkv(
    const unsigned short* __restrict__ xb,
    const unsigned short* __restrict__ wqb, const unsigned short* __restrict__ wkb,
    const unsigned short* __restrict__ wvb,
    unsigned short* __restrict__ Qb, unsigned short* __restrict__ Kb,
    unsigned short* __restrict__ Vt) {
  constexpr int BM = 128, BN = 128, BK = 32;
  __shared__ unsigned short As[BM * BK];
  __shared__ unsigned short Bs[BN * BK];
  const int z = blockIdx.z;
  const unsigned short* W = (z == 0) ? wqb : (z == 1) ? wkb : wvb;
  const int m0 = blockIdx.x * BM, n0 = blockIdx.y * BN;
  const int tid = threadIdx.x, w = tid >> 6, lane = tid & 63;
  const int quad = lane >> 4, l16 = lane & 15;
  const int wm = w >> 1, wn = w & 1;
  const int srow = lane >> 2, skoff = (lane & 3) * 8;

  floatx4 acc[4][4] = {};

  for (int kt = 0; kt < EMB / BK; ++kt) {
    const int k0 = kt * BK;
#pragma unroll
    for (int i = 0; i < BM / 64; ++i) {
      int r = i * 64 + w * 16;
      gl_lds16(xb + (size_t)(m0 + r + srow) * EMB + k0 + skoff, &As[r * BK]);
    }
#pragma unroll
    for (int i = 0; i < BN / 64; ++i) {
      int r = i * 64 + w * 16;
      gl_lds16(W + (size_t)(n0 + r + srow) * EMB + k0 + skoff, &Bs[r * BK]);
    }
    __syncthreads();
    bf16x8 af[4], bfv[4];
#pragma unroll
    for (int mb = 0; mb < 4; ++mb)
      af[mb] = *(const bf16x8*)&As[(wm * 64 + mb * 16 + l16) * BK + quad * 8];
#pragma unroll
    for (int nb = 0; nb < 4; ++nb)
      bfv[nb] = *(const bf16x8*)&Bs[(wn * 64 + nb * 16 + l16) * BK + quad * 8];
#pragma unroll
    for (int mb = 0; mb < 4; ++mb)
#pragma unroll
      for (int nb = 0; nb < 4; ++nb)
        acc[mb][nb] = __builtin_amdgcn_mfma_f32_16x16x32_bf16(af[mb], bfv[nb], acc[mb][nb], 0, 0, 0);
    __syncthreads();
  }

  if (z < 2) {
    unsigned short* C = (z == 0) ? Qb : Kb;
    const float scale = (z == 0) ? 0.180336876f : 1.0f;  // 0.125 * log2(e) folded into Q
#pragma unroll
    for (int mb = 0; mb < 4; ++mb) {
#pragma unroll
      for (int nb = 0; nb < 4; ++nb) {
        int n = n0 + wn * 64 + nb * 16 + l16;
#pragma unroll
        for (int r = 0; r < 4; ++r) {
          int m = m0 + wm * 64 + mb * 16 + quad * 4 + r;
          C[(size_t)m * EMB + n] = f2bf(acc[mb][nb][r] * scale);
        }
      }
    }
  } else {
    // transposed store: Vt[(b*1024 + n)][s], n = h*64+d, 4 consecutive s per lane
#pragma unroll
    for (int mb = 0; mb < 4; ++mb) {
      int mbase = m0 + wm * 64 + mb * 16 + quad * 4;
      int b = mbase >> 11, s = mbase & (SEQ - 1);
#pragma unroll
      for (int nb = 0; nb < 4; ++nb) {
        int n = n0 + wn * 64 + nb * 16 + l16;
        ushort4 o;
        o.x = f2bf(acc[mb][nb][0]); o.y = f2bf(acc[mb][nb][1]);
        o.z = f2bf(acc[mb][nb][2]); o.w = f2bf(acc[mb][nb][3]);
        *(ushort4*)&Vt[((size_t)b * (HEADS * DHEAD) + n) * SEQ + s] = o;
      }
    }
  }
}

// ---------------- flash-style causal attention, v2 ----------------
// QT=64, KT=128. grid (pair=16, bh=32): block does q-tiles {pair, 31-pair} ->
// uniform 17 k-tiles per block. K/V staged in MFMA-fragment order (conflict-free
// b128 reads); Ps padded (stride 136). 2 syncthreads per k-tile.
__global__ __launch_bounds__(256) void attn_kernel(
    const unsigned short* __restrict__ Qb, const unsigned short* __restrict__ Kb,
    const unsigned short* __restrict__ Vt, unsigned short* __restrict__ ctx) {
  constexpr int KT = 128;
  constexpr int PST = KT + 8;                     // padded row stride (ushorts)
  __shared__ unsigned short Ks[KT * DHEAD];       // fragment order: (f*64+lane)*8
  __shared__ unsigned short Vs[DHEAD * KT];       // fragment order
  __shared__ __bf16 Ps[4 * 16 * PST];             // per-wave [16][PST]
  const int pair = blockIdx.x, bh = blockIdx.y;
  const int b = bh >> 4, h = bh & 15;
  const int tid = threadIdx.x, w = tid >> 6, lane = tid & 63;
  const int quad = lane >> 4, l16 = lane & 15;

  const unsigned short* Kbh = Kb + (size_t)b * SEQ * EMB + h * DHEAD;
  const unsigned short* Vbh = Vt + (size_t)bh * DHEAD * SEQ;
  __bf16* Pw = &Ps[w * (16 * PST)];

  // per-lane staging coordinates (chunk c = i*256 + tid, lane = c&63)
  int kq[4], kd[4], vd[4], vk[4];
#pragma unroll
  for (int i = 0; i < 4; ++i) {
    int c = i * 256 + tid;
    kq[i] = ((c >> 6) & 7) * 16 + (c & 15);       // key row within tile (K)
    kd[i] = ((c >> 9) << 5) + (((c >> 4) & 3) << 3);  // d offset (K)
    vd[i] = (((c >> 6) & 3) << 4) + (c & 15);     // d row (V^T)
    vk[i] = (((c >> 8) & 3) << 5) + (((c >> 4) & 3) << 3);  // key offset (V^T)
  }

  for (int pi = 0; pi < 2; ++pi) {
    const int qt = pi ? (31 - pair) : pair;
    const int q0 = qt * 64;
    const int myrow = q0 + w * 16 + quad * 4;     // this lane's 4 rows start

    const size_t qrow = (size_t)(b * SEQ + q0 + w * 16 + l16) * EMB + h * DHEAD;
    bf16x8 qf[2];
    qf[0] = *(const bf16x8*)&Qb[qrow + quad * 8];
    qf[1] = *(const bf16x8*)&Qb[qrow + 32 + quad * 8];

    float mrow[4], lrow[4];
    floatx4 acc_o[4] = {};
#pragma unroll
    for (int r = 0; r < 4; ++r) { mrow[r] = -1e30f; lrow[r] = 0.0f; }

    const int nkt = (qt + 2) >> 1;                // ceil((qt+1)*64/128)
    for (int ktile = 0; ktile < nkt; ++ktile) {
      const int kt0 = ktile * KT;
      // ---- stage K (16KB) + V (16KB) in fragment order ----
#pragma unroll
      for (int i = 0; i < 4; ++i) {
        gl_lds16(Kbh + (size_t)(kt0 + kq[i]) * EMB + kd[i], &Ks[(i * 256 + w * 64) * 8]);
        gl_lds16(Vbh + (size_t)vd[i] * SEQ + kt0 + vk[i], &Vs[(i * 256 + w * 64) * 8]);
      }
      __syncthreads();

      // ---- S = Q K^T : 16 rows x 128 keys per wave ----
      floatx4 accs[8] = {};
#pragma unroll
      for (int ks = 0; ks < 2; ++ks)
#pragma unroll
        for (int nb = 0; nb < 8; ++nb) {
          bf16x8 kf = *(const bf16x8*)&Ks[((ks * 8 + nb) * 64 + lane) * 8];
          accs[nb] = __builtin_amdgcn_mfma_f32_16x16x32_bf16(qf[ks], kf, accs[nb], 0, 0, 0);
        }

      const bool diag = (ktile == nkt - 1);
      // ---- online softmax (exp2 domain; scale pre-folded into Q) ----
#pragma unroll
      for (int r = 0; r < 4; ++r) {
        float sv[8];
#pragma unroll
        for (int nb = 0; nb < 8; ++nb) sv[nb] = accs[nb][r];
        if (diag) {
          int row = myrow + r;
#pragma unroll
          for (int nb = 0; nb < 8; ++nb) {
            int col = kt0 + nb * 16 + l16;
            if (col > row) sv[nb] = -1e30f;
          }
        }
        float rm = sv[0];
#pragma unroll
        for (int nb = 1; nb < 8; ++nb) rm = fmaxf(rm, sv[nb]);
        rm = fmaxf(rm, __shfl_xor(rm, 1));
        rm = fmaxf(rm, __shfl_xor(rm, 2));
        rm = fmaxf(rm, __shfl_xor(rm, 4));
        rm = fmaxf(rm, __shfl_xor(rm, 8));
        float mnew = fmaxf(mrow[r], rm);
        float alpha = EXP2(mrow[r] - mnew);
        float rs = 0.0f;
#pragma unroll
        for (int nb = 0; nb < 8; ++nb) {
          float pe = EXP2(sv[nb] - mnew);
          Pw[(quad * 4 + r) * PST + nb * 16 + l16] = (__bf16)pe;
          rs += pe;
        }
        rs += __shfl_xor(rs, 1);
        rs += __shfl_xor(rs, 2);
        rs += __shfl_xor(rs, 4);
        rs += __shfl_xor(rs, 8);
        lrow[r] = lrow[r] * alpha + rs;
        mrow[r] = mnew;
#pragma unroll
        for (int nb = 0; nb < 4; ++nb) acc_o[nb][r] *= alpha;
      }

      // ---- O += P V  (Ps is wave-private: no barrier needed) ----
#pragma unroll
      for (int ks = 0; ks < 4; ++ks) {
        bf16x8 pf = *(const bf16x8*)&Pw[l16 * PST + ks * 32 + quad * 8];
#pragma unroll
        for (int nb = 0; nb < 4; ++nb) {
          bf16x8 vf = *(const bf16x8*)&Vs[((ks * 4 + nb) * 64 + lane) * 8];
          acc_o[nb] = __builtin_amdgcn_mfma_f32_16x16x32_bf16(pf, vf, acc_o[nb], 0, 0, 0);
        }
      }
      __syncthreads();   // all waves done with Ks/Vs before next staging
    }

    // ---- normalize + write ctx [tok][E] ----
#pragma unroll
    for (int r = 0; r < 4; ++r) {
      float inv = 1.0f / lrow[r];
      size_t base = (size_t)(b * SEQ + myrow + r) * EMB + h * DHEAD;
#pragma unroll
      for (int nb = 0; nb < 4; ++nb)
        ctx[base + nb * 16 + l16] = f2bf(acc_o[nb][r] * inv);
    }
  }
}

// ---------------- output projection: out = ctx @ Wu^T + bu (fp32 out) ----------------
// 128x64 tile -> 512 blocks for occupancy; wave tile 64x32 (4x2 MFMA grid).
__global__ __launch_bounds__(256) void gemm_out(
    const unsigned short* __restrict__ ctx, const unsigned short* __restrict__ wub,
    const float* __restrict__ bu, float* __restrict__ out) {
  constexpr int BM = 128, BN = 64, BK = 32;
  __shared__ unsigned short As[BM * BK];
  __shared__ unsigned short Bs[BN * BK];
  const int m0 = blockIdx.x * BM, n0 = blockIdx.y * BN;
  const int tid = threadIdx.x, w = tid >> 6, lane = tid & 63;
  const int quad = lane >> 4, l16 = lane & 15;
  const int wm = w >> 1, wn = w & 1;
  const int srow = lane >> 2, skoff = (lane & 3) * 8;

  floatx4 acc[4][2] = {};

  for (int kt = 0; kt < EMB / BK; ++kt) {
    const int k0 = kt * BK;
#pragma unroll
    for (int i = 0; i < 2; ++i) {
      int r = i * 64 + w * 16;
      gl_lds16(ctx + (size_t)(m0 + r + srow) * EMB + k0 + skoff, &As[r * BK]);
    }
    gl_lds16(wub + (size_t)(n0 + w * 16 + srow) * EMB + k0 + skoff, &Bs[(w * 16) * BK]);
    __syncthreads();
    bf16x8 af[4], bfv[2];
#pragma unroll
    for (int mb = 0; mb < 4; ++mb)
      af[mb] = *(const bf16x8*)&As[(wm * 64 + mb * 16 + l16) * BK + quad * 8];
#pragma unroll
    for (int nb = 0; nb < 2; ++nb)
      bfv[nb] = *(const bf16x8*)&Bs[(wn * 32 + nb * 16 + l16) * BK + quad * 8];
#pragma unroll
    for (int mb = 0; mb < 4; ++mb)
#pragma unroll
      for (int nb = 0; nb < 2; ++nb)
        acc[mb][nb] = __builtin_amdgcn_mfma_f32_16x16x32_bf16(af[mb], bfv[nb], acc[mb][nb], 0, 0, 0);
    __syncthreads();
  }

#pragma unroll
  for (int mb = 0; mb < 4; ++mb) {
#pragma unroll
    for (int nb = 0; nb < 2; ++nb) {
      int n = n0 + wn * 32 + nb * 16 + l16;
      float bias = bu[n];
#pragma unroll
      for (int r = 0; r < 4; ++r) {
        int m = m0 + wm * 64 + mb * 16 + quad * 4 + r;
        out[(size_t)m * EMB + n] = acc[mb][nb][r] + bias;
      }
    }
  }
}

extern "C" void kernel_launch(void* const* d_in, const int* in_sizes, int n_in,
                              void* d_out, int out_size, void* d_ws, size_t ws_size,
                              hipStream_t stream) {
  // setup_inputs order: x, Wk, Wq, Wv, Wu, bu
  const float* x  = (const float*)d_in[0];
  const float* Wk = (const float*)d_in[1];
  const float* Wq = (const float*)d_in[2];
  const float* Wv = (const float*)d_in[3];
  const float* Wu = (const float*)d_in[4];
  const float* bu = (const float*)d_in[5];

  char* ws = (char*)d_ws;
  const size_t MB1 = 1 << 20;
  unsigned short* xb  = (unsigned short*)(ws + 0);
  unsigned short* wqb = (unsigned short*)(ws + 8  * MB1);
  unsigned short* wkb = (unsigned short*)(ws + 10 * MB1);
  unsigned short* wvb = (unsigned short*)(ws + 12 * MB1);
  unsigned short* wub = (unsigned short*)(ws + 14 * MB1);
  unsigned short* Qb  = (unsigned short*)(ws + 16 * MB1);
  unsigned short* Kb  = (unsigned short*)(ws + 24 * MB1);
  unsigned short* Vt  = (unsigned short*)(ws + 32 * MB1);
  unsigned short* ctx = (unsigned short*)(ws + 40 * MB1);

  cvt_kernel<<<8192, 256, 0, stream>>>(x, Wq, Wk, Wv, Wu, xb, wqb, wkb, wvb, wub);
  gemm_qkv<<<dim3(32, 8, 3), 256, 0, stream>>>(xb, wqb, wkb, wvb, Qb, Kb, Vt);
  attn_kernel<<<dim3(16, 32), 256, 0, stream>>>(Qb, Kb, Vt, ctx);
  gemm_out<<<dim3(32, 16), 256, 0, stream>>>(ctx, wub, bu, (float*)d_out);
}